// Round 15
// baseline (1496.536 us; speedup 1.0000x reference)
//
#include <hip/hip_runtime.h>
#include <math.h>

#define N_NODES 8000
#define N_EDGES 256000
#define NSTEPS 10
#define LO_SCALE 4096.0f
#define LO_INV   (1.0f/4096.0f)

typedef unsigned short u16;
typedef unsigned int   u32;
typedef _Float16 h8_t __attribute__((ext_vector_type(8)));
typedef float f32x4 __attribute__((ext_vector_type(4)));

#define MFMA(a, b, c) __builtin_amdgcn_mfma_f32_16x16x32_f16((a), (b), (c), 0, 0, 0)

// x ~= hi + lo/4096, relative error ~2^-22 (lo scaled to stay fp16-normal)
__device__ __forceinline__ void split2(float x, u16& hi, u16& lo) {
    _Float16 h = (_Float16)x;
    _Float16 l = (_Float16)((x - (float)h) * LO_SCALE);
    hi = __builtin_bit_cast(u16, h);
    lo = __builtin_bit_cast(u16, l);
}
__device__ __forceinline__ float h2f(u16 u) {
    return (float)__builtin_bit_cast(_Float16, u);
}
__device__ __forceinline__ float joinv(u16 hi, u16 lo) {
    return h2f(hi) + h2f(lo) * LO_INV;
}

union U8 { u16 s[8]; uint4 v; };

// ---------------- one-time prep kernels ----------------

__global__ __launch_bounds__(256)
void prep_edges_k(const float* __restrict__ J,
                  const int* __restrict__ row, const int* __restrict__ col,
                  float* __restrict__ jvv, float* __restrict__ degf) {
    int idx = blockIdx.x * 256 + threadIdx.x;
    if (idx < N_EDGES) {
        int r = row[idx], c = col[idx];
        jvv[idx] = J[(long)r * N_NODES + c];
        atomicAdd(&degf[r], 1.0f);
    }
}

// W2 pairs [128][128]; W1ab pairs [256][64]; W3 pairs [64][128];
// extraW f32 [4][128] = {Wm1[:,128], Wm1[:,129], Wm1[:,130], bm1};
// Wih pairs [192][64]; Whh pairs [192][64]  (torch-native row-major [out][in])
__global__ __launch_bounds__(256)
void convw_k(const float* __restrict__ Wm1, const float* __restrict__ bm1,
             const float* __restrict__ Wm2, const float* __restrict__ Wm3,
             const float* __restrict__ W_ih, const float* __restrict__ W_hh,
             u16* __restrict__ W2_h,  u16* __restrict__ W2_l,
             u16* __restrict__ Wab_h, u16* __restrict__ Wab_l,
             u16* __restrict__ W3_h,  u16* __restrict__ W3_l,
             u16* __restrict__ Wih_h, u16* __restrict__ Wih_l,
             u16* __restrict__ Whh_h, u16* __restrict__ Whh_l,
             float* __restrict__ extraW) {
    int i = blockIdx.x * 256 + threadIdx.x;
    u16 hi, lo;
    if (i < 16384) {                       // W2 [j][k]
        split2(Wm2[i], hi, lo);
        W2_h[i] = hi; W2_l[i] = lo;
    } else if (i < 32768) {                // W1ab [256][64]
        int t = i - 16384; int j = t >> 6, k = t & 63;
        float src = (j < 128) ? Wm1[j * 131 + k] : Wm1[(j - 128) * 131 + 64 + k];
        split2(src, hi, lo);
        Wab_h[t] = hi; Wab_l[t] = lo;
    } else if (i < 40960) {                // W3 [64][128]
        int t = i - 32768;
        split2(Wm3[t], hi, lo);
        W3_h[t] = hi; W3_l[t] = lo;
    } else if (i < 41472) {                // extraW
        int t = i - 40960; int rr = t >> 7, j = t & 127;
        extraW[t] = (rr < 3) ? Wm1[j * 131 + 128 + rr] : bm1[j];
    } else if (i < 53760) {                // Wih [192][64]
        int t = i - 41472;
        split2(W_ih[t], hi, lo);
        Wih_h[t] = hi; Wih_l[t] = lo;
    } else if (i < 66048) {                // Whh [192][64]
        int t = i - 53760;
        split2(W_hh[t], hi, lo);
        Whh_h[t] = hi; Whh_l[t] = lo;
    }
}

// out[k*O + j] = in[j*K + k]
__global__ __launch_bounds__(256)
void transpose_k(const float* __restrict__ in, float* __restrict__ out, int O, int K) {
    int idx = blockIdx.x * 256 + threadIdx.x;
    if (idx < O * K) {
        int j = idx / K, k = idx - j * K;
        out[k * O + j] = in[idx];
    }
}

// ---------------- register-B pair-GEMM core (verified frag layout) ----------------

template <int NT, int K0>
__device__ __forceinline__ void load_bfrags(const u16* __restrict__ Wh,
                                            const u16* __restrict__ Wl,
                                            int wn, int l15, int g,
                                            h8_t (&bh)[NT][K0], h8_t (&bl)[NT][K0]) {
    #pragma unroll
    for (int jt = 0; jt < NT; jt++)
        #pragma unroll
        for (int k0 = 0; k0 < K0; k0++) {
            int off = (wn + jt * 16 + l15) * (K0 * 32) + k0 * 32 + g * 8;
            bh[jt][k0] = *(const h8_t*)(Wh + off);
            bl[jt][k0] = *(const h8_t*)(Wl + off);
        }
}

// A from swizzled LDS (chunk c of row r at (r*CH + (c^(r&7)))*8), B in registers.
template <int NT, int K0, int CH>
__device__ __forceinline__ void gemm_regB(const u16* Ah, const u16* Al,
                                          const h8_t (&bh)[NT][K0],
                                          const h8_t (&bl)[NT][K0],
                                          int et, int l15, int g,
                                          f32x4 (&accH)[NT], f32x4 (&accC)[NT]) {
    #pragma unroll
    for (int k0 = 0; k0 < K0; k0++) {
        int r = et * 16 + l15;
        int off = (r * CH + ((k0 * 4 + g) ^ (r & 7))) * 8;
        h8_t a_h = *(const h8_t*)(Ah + off);
        h8_t a_l = *(const h8_t*)(Al + off);
        #pragma unroll
        for (int jt = 0; jt < NT; jt++) {
            accH[jt] = MFMA(a_h, bh[jt][k0], accH[jt]);
            accC[jt] = MFMA(a_h, bl[jt][k0], accC[jt]);
            accC[jt] = MFMA(a_l, bh[jt][k0], accC[jt]);
        }
    }
}

// ---------------- edge kernel v7: single barrier, register-scatter ----------------
// 64 edges/block, 512 threads, 8 waves; wave w owns j-tile [w*16, w*16+16).
// After the GEMM each lane holds 4 consecutive edges (et*16+g*4+r) at one j:
// run-accumulate in registers (rows sorted) and atomicAdd per run-break.
__global__ __launch_bounds__(512, 6)
void msg7_k(const float* __restrict__ PQ,
            const int* __restrict__ row, const int* __restrict__ col,
            const float* __restrict__ jvv, const float* __restrict__ extraW,
            const u16* __restrict__ W2_h, const u16* __restrict__ W2_l,
            const float* __restrict__ bm2,
            float* __restrict__ nm2) {
    __shared__ u16 AB[2][64 * 128];        // t1 pairs (32 KB)
    __shared__ int rws[64];
    const u16* Ah = AB[0];
    const u16* Al = AB[1];
    const int tid  = threadIdx.x;
    // XCD-aware bijective swizzle: 4000 blocks = 8 XCDs x 500 contiguous
    const int bid  = blockIdx.x;
    const int e0   = ((bid & 7) * 500 + (bid >> 3)) * 64;
    const int lane = tid & 63;
    const int w    = tid >> 6;
    const int l15  = lane & 15;
    const int g    = lane >> 4;

    // W2 fragments for this wave's 16-wide j-tile (8 x h8_t = 32 VGPR)
    h8_t bh[1][4], bl[1][4];
    load_bfrags<1, 4>(W2_h, W2_l, w * 16, l15, g, bh, bl);

    // ---- t1 assembly: thread -> edge e=tid>>3, j-eighth jq=tid&7 ----
    {
        int e = tid >> 3, jq = tid & 7;
        int nr = row[e0 + e], nc = col[e0 + e];
        float jv = jvv[e0 + e];
        if (jq == 0) rws[e] = nr;
        const float* Pp = PQ + nr * 256;          // P' = h@W1a^T + b*w129 + bm1
        const float* Qp = PQ + nc * 256 + 128;    // Q' = h@W1b^T + b*w130
        #pragma unroll
        for (int cc = 0; cc < 2; cc++) {
            int jb = jq * 16 + cc * 8;
            float4 p0 = *(const float4*)(Pp + jb);
            float4 p1 = *(const float4*)(Pp + jb + 4);
            float4 q0 = *(const float4*)(Qp + jb);
            float4 q1 = *(const float4*)(Qp + jb + 4);
            float4 wA = *(const float4*)(extraW + jb);
            float4 wB = *(const float4*)(extraW + jb + 4);
            float pv[8] = {p0.x, p0.y, p0.z, p0.w, p1.x, p1.y, p1.z, p1.w};
            float qv[8] = {q0.x, q0.y, q0.z, q0.w, q1.x, q1.y, q1.z, q1.w};
            float wv[8] = {wA.x, wA.y, wA.z, wA.w, wB.x, wB.y, wB.z, wB.w};
            U8 uh, ul;
            #pragma unroll
            for (int m = 0; m < 8; m++) {
                float v = fmaxf(pv[m] + qv[m] + jv * wv[m], 0.f);
                u16 hi, lo; split2(v, hi, lo);
                uh.s[m] = hi; ul.s[m] = lo;
            }
            int c = jq * 2 + cc;
            int dst = (e * 16 + (c ^ (e & 7))) * 8;
            *(uint4*)(AB[0] + dst) = uh.v;
            *(uint4*)(AB[1] + dst) = ul.v;
        }
    }
    __syncthreads();          // the only barrier

    // ---- layer 2 GEMM + fused register-scatter, per et-tile ----
    const int j = w * 16 + l15;
    const float bv0 = bm2[j];
    #pragma unroll
    for (int et = 0; et < 4; et++) {
        f32x4 accH[1], accC[1];
        accH[0] = f32x4{bv0, bv0, bv0, bv0};
        accC[0] = f32x4{0.f, 0.f, 0.f, 0.f};
        gemm_regB<1, 4, 16>(Ah, Al, bh, bl, et, l15, g, accH, accC);

        int ebase = et * 16 + g * 4;
        float a  = fmaxf(accH[0][0] + accC[0][0] * LO_INV, 0.f);
        int  cur = rws[ebase];
        #pragma unroll
        for (int r = 1; r < 4; r++) {
            int   rr = rws[ebase + r];
            float v  = fmaxf(accH[0][r] + accC[0][r] * LO_INV, 0.f);
            if (rr != cur) {
                atomicAdd(&nm2[cur * 128 + j], a);
                a = v; cur = rr;
            } else {
                a += v;
            }
        }
        atomicAdd(&nm2[cur * 128 + j], a);
    }
}

// ---------------- fused node kernel: nodeL3 + GRU + embed (16 nodes/block) ----------------
__global__ __launch_bounds__(256)
void nodeGRU_k(float* __restrict__ nm2, const float* __restrict__ degf,
               const u16* __restrict__ W3_h, const u16* __restrict__ W3_l,
               const float* __restrict__ bm3,
               const u16* __restrict__ Wih_h, const u16* __restrict__ Wih_l,
               const u16* __restrict__ Whh_h, const u16* __restrict__ Whh_l,
               const float* __restrict__ b_ih, const float* __restrict__ b_hh,
               const u16* __restrict__ Wab_h, const u16* __restrict__ Wab_l,
               const float* __restrict__ bvec, const float* __restrict__ extraW,
               u16* __restrict__ h_hi, u16* __restrict__ h_lo,
               float* __restrict__ PQ) {
    __shared__ u16 nm2A[2][16 * 128];   // 8 KB  (nm2 pairs, CH=16)
    __shared__ u16 hA[2][16 * 64];      // 4 KB  (h pairs,   CH=8)
    __shared__ u16 nmA[2][16 * 64];     // 4 KB  (nm pairs,  CH=8)
    __shared__ u16 hnA[2][16 * 64];     // 4 KB  (h_new pairs, CH=8)
    const int tid = threadIdx.x;
    const int n0  = blockIdx.x * 16;
    const int lane = tid & 63, w = tid >> 6, l15 = lane & 15, g = lane >> 4;

    // ---- phase 0: stage nm2 pairs (and zero nm2), stage h pairs ----
    {
        int n = tid >> 4, kq = tid & 15;       // 16 nodes x 16 chunks
        float* src = nm2 + (n0 + n) * 128 + kq * 8;
        U8 uh, ul;
        #pragma unroll
        for (int m = 0; m < 8; m++) {
            u16 hi, lo; split2(src[m], hi, lo);
            uh.s[m] = hi; ul.s[m] = lo;
        }
        int dst = (n * 16 + (kq ^ (n & 7))) * 8;
        *(uint4*)(nm2A[0] + dst) = uh.v;
        *(uint4*)(nm2A[1] + dst) = ul.v;
        #pragma unroll
        for (int m = 0; m < 2; m++)
            ((f32x4*)src)[m] = f32x4{0.f, 0.f, 0.f, 0.f};   // clear for next step
        if (tid < 128) {
            int nh = tid >> 3, c = tid & 7;
            int dsth = (nh * 8 + (c ^ (nh & 7))) * 8;
            *(uint4*)(hA[0] + dsth) = *(const uint4*)(h_hi + (n0 + nh) * 64 + c * 8);
            *(uint4*)(hA[1] + dsth) = *(const uint4*)(h_lo + (n0 + nh) * 64 + c * 8);
        }
    }
    __syncthreads();

    // ---- phase 1: nm = nm2 @ W3^T + deg*bm3  -> nmA pairs ----
    {
        h8_t bh[1][4], bl[1][4];
        load_bfrags<1, 4>(W3_h, W3_l, w * 16, l15, g, bh, bl);
        const int j = w * 16 + l15;
        const float bj = bm3[j];
        f32x4 accH[1], accC[1];
        accH[0] = f32x4{0.f, 0.f, 0.f, 0.f};
        accC[0] = f32x4{0.f, 0.f, 0.f, 0.f};
        gemm_regB<1, 4, 16>(nm2A[0], nm2A[1], bh, bl, 0, l15, g, accH, accC);
        #pragma unroll
        for (int r = 0; r < 4; r++) {
            int n = g * 4 + r;
            float v = accH[0][r] + accC[0][r] * LO_INV + degf[n0 + n] * bj;
            u16 hi, lo; split2(v, hi, lo);
            int addr = (n * 8 + ((j >> 3) ^ (n & 7))) * 8 + (j & 7);
            nmA[0][addr] = hi; nmA[1][addr] = lo;
        }
    }
    __syncthreads();

    // ---- phase 2: GRU via MFMA; wave w owns d-tile [w*16, w*16+16) ----
    {
        h8_t bihH[3][2], bihL[3][2], bhhH[3][2], bhhL[3][2];
        #pragma unroll
        for (int gate = 0; gate < 3; gate++)
            #pragma unroll
            for (int k0 = 0; k0 < 2; k0++) {
                int off = (gate * 64 + w * 16 + l15) * 64 + k0 * 32 + g * 8;
                bihH[gate][k0] = *(const h8_t*)(Wih_h + off);
                bihL[gate][k0] = *(const h8_t*)(Wih_l + off);
                bhhH[gate][k0] = *(const h8_t*)(Whh_h + off);
                bhhL[gate][k0] = *(const h8_t*)(Whh_l + off);
            }
        const int d = w * 16 + l15;
        const float bi0 = b_ih[d], bi1 = b_ih[64 + d], bi2 = b_ih[128 + d];
        const float bh0 = b_hh[d], bh1 = b_hh[64 + d], bh2 = b_hh[128 + d];

        f32x4 giH[3], giC[3], ghH[3], ghC[3];
        giH[0] = f32x4{bi0, bi0, bi0, bi0};
        giH[1] = f32x4{bi1, bi1, bi1, bi1};
        giH[2] = f32x4{bi2, bi2, bi2, bi2};
        ghH[0] = f32x4{bh0, bh0, bh0, bh0};
        ghH[1] = f32x4{bh1, bh1, bh1, bh1};
        ghH[2] = f32x4{bh2, bh2, bh2, bh2};
        #pragma unroll
        for (int gate = 0; gate < 3; gate++) {
            giC[gate] = f32x4{0.f, 0.f, 0.f, 0.f};
            ghC[gate] = f32x4{0.f, 0.f, 0.f, 0.f};
        }
        #pragma unroll
        for (int k0 = 0; k0 < 2; k0++) {
            int off = (l15 * 8 + ((k0 * 4 + g) ^ (l15 & 7))) * 8;
            h8_t anH = *(const h8_t*)(nmA[0] + off);
            h8_t anL = *(const h8_t*)(nmA[1] + off);
            h8_t ahH = *(const h8_t*)(hA[0] + off);
            h8_t ahL = *(const h8_t*)(hA[1] + off);
            #pragma unroll
            for (int gate = 0; gate < 3; gate++) {
                giH[gate] = MFMA(anH, bihH[gate][k0], giH[gate]);
                giC[gate] = MFMA(anH, bihL[gate][k0], giC[gate]);
                giC[gate] = MFMA(anL, bihH[gate][k0], giC[gate]);
                ghH[gate] = MFMA(ahH, bhhH[gate][k0], ghH[gate]);
                ghC[gate] = MFMA(ahH, bhhL[gate][k0], ghC[gate]);
                ghC[gate] = MFMA(ahL, bhhH[gate][k0], ghC[gate]);
            }
        }
        #pragma unroll
        for (int r = 0; r < 4; r++) {
            int n = g * 4 + r;
            float i_r = giH[0][r] + giC[0][r] * LO_INV;
            float i_z = giH[1][r] + giC[1][r] * LO_INV;
            float i_n = giH[2][r] + giC[2][r] * LO_INV;
            float h_r = ghH[0][r] + ghC[0][r] * LO_INV;
            float h_z = ghH[1][r] + ghC[1][r] * LO_INV;
            float h_n = ghH[2][r] + ghC[2][r] * LO_INV;
            int addr = (n * 8 + ((d >> 3) ^ (n & 7))) * 8 + (d & 7);
            float hv = joinv(hA[0][addr], hA[1][addr]);
            float rg = 1.f / (1.f + expf(-(i_r + h_r)));
            float zg = 1.f / (1.f + expf(-(i_z + h_z)));
            float ng = tanhf(i_n + rg * h_n);
            float v  = (1.f - zg) * ng + zg * hv;
            u16 hi, lo; split2(v, hi, lo);
            h_hi[(n0 + n) * 64 + d] = hi;
            h_lo[(n0 + n) * 64 + d] = lo;
            hnA[0][addr] = hi; hnA[1][addr] = lo;
        }
    }
    __syncthreads();

    // ---- phase 3: PQ = h_new @ [W1a|W1b]^T + folded b-terms (f32 out) ----
    {
        h8_t bh[4][2], bl[4][2];
        load_bfrags<4, 2>(Wab_h, Wab_l, w * 64, l15, g, bh, bl);
        f32x4 accH[4], accC[4];
        #pragma unroll
        for (int jt = 0; jt < 4; jt++) {
            accH[jt] = f32x4{0.f, 0.f, 0.f, 0.f};
            accC[jt] = f32x4{0.f, 0.f, 0.f, 0.f};
        }
        gemm_regB<4, 2, 8>(hnA[0], hnA[1], bh, bl, 0, l15, g, accH, accC);
        #pragma unroll
        for (int jt = 0; jt < 4; jt++) {
            int j = w * 64 + jt * 16 + l15;
            #pragma unroll
            for (int r = 0; r < 4; r++) {
                int n = g * 4 + r;
                float bn = bvec[n0 + n];
                float v = accH[jt][r] + accC[jt][r] * LO_INV;
                if (j < 128) v += bn * extraW[128 + j] + extraW[384 + j];
                else         v += bn * extraW[256 + (j - 128)];
                PQ[(n0 + n) * 256 + j] = v;
            }
        }
    }
}

// ---------------- node kernel: initial PQ (h=0), f32 out ----------------
__global__ __launch_bounds__(256)
void embed_k(const u16* __restrict__ h_hi, const u16* __restrict__ h_lo,
             const u16* __restrict__ Wab_h, const u16* __restrict__ Wab_l,
             const float* __restrict__ bvec, const float* __restrict__ extraW,
             float* __restrict__ PQ) {
    __shared__ u16 AB[2][64 * 64];
    const u16* Ah = AB[0];
    const u16* Al = AB[1];
    const int tid = threadIdx.x;
    const int n0  = blockIdx.x * 64;
    const int lane = tid & 63, w = tid >> 6, l15 = lane & 15, g = lane >> 4;

    h8_t bh[4][2], bl[4][2];
    load_bfrags<4, 2>(Wab_h, Wab_l, w * 64, l15, g, bh, bl);

    {
        int n = tid >> 2, seg = tid & 3;
        #pragma unroll
        for (int cc = 0; cc < 2; cc++) {
            int c = seg * 2 + cc;
            int dst = (n * 8 + (c ^ (n & 7))) * 8;
            *(uint4*)(AB[0] + dst) = *(const uint4*)(h_hi + (n0 + n) * 64 + c * 8);
            *(uint4*)(AB[1] + dst) = *(const uint4*)(h_lo + (n0 + n) * 64 + c * 8);
        }
    }
    __syncthreads();

    #pragma unroll
    for (int et = 0; et < 4; et++) {
        f32x4 accH[4], accC[4];
        #pragma unroll
        for (int jt = 0; jt < 4; jt++) {
            accH[jt] = f32x4{0.f, 0.f, 0.f, 0.f};
            accC[jt] = f32x4{0.f, 0.f, 0.f, 0.f};
        }
        gemm_regB<4, 2, 8>(Ah, Al, bh, bl, et, l15, g, accH, accC);
        #pragma unroll
        for (int jt = 0; jt < 4; jt++) {
            int j = w * 64 + jt * 16 + l15;
            #pragma unroll
            for (int r = 0; r < 4; r++) {
                int n = et * 16 + g * 4 + r;
                float bn = bvec[n0 + n];
                float v = accH[jt][r] + accC[jt][r] * LO_INV;
                if (j < 128) v += bn * extraW[128 + j] + extraW[384 + j];
                else         v += bn * extraW[256 + (j - 128)];
                PQ[(n0 + n) * 256 + j] = v;
            }
        }
    }
}

// ---------------- readout MLP + softmax ----------------
__global__ __launch_bounds__(256)
void readout_k(const u16* __restrict__ h_hi, const u16* __restrict__ h_lo,
               const float* __restrict__ Wr1t, const float* __restrict__ br1,
               const float* __restrict__ Wr2t, const float* __restrict__ br2,
               const float* __restrict__ Wr3,  const float* __restrict__ br3,
               float* __restrict__ out) {
    __shared__ float hs[4][64], r1s[4][128];
    int tid = threadIdx.x, g = tid >> 6, d = tid & 63;
    int n = blockIdx.x * 4 + g;
    hs[g][d] = joinv(h_hi[n * 64 + d], h_lo[n * 64 + d]);
    __syncthreads();
    float a0 = br1[d], a1 = br1[64 + d];
    for (int k = 0; k < 64; k++) {
        float v = hs[g][k];
        a0 = fmaf(v, Wr1t[k * 128 + d],      a0);
        a1 = fmaf(v, Wr1t[k * 128 + 64 + d], a1);
    }
    r1s[g][d] = fmaxf(a0, 0.f); r1s[g][64 + d] = fmaxf(a1, 0.f);
    __syncthreads();
    a0 = br2[d]; a1 = br2[64 + d];
    for (int k = 0; k < 128; k++) {
        float v = r1s[g][k];
        a0 = fmaf(v, Wr2t[k * 128 + d],      a0);
        a1 = fmaf(v, Wr2t[k * 128 + 64 + d], a1);
    }
    float q0 = fmaxf(a0, 0.f), q1 = fmaxf(a1, 0.f);
    float p0 = q0 * Wr3[d]       + q1 * Wr3[64 + d];
    float p1 = q0 * Wr3[128 + d] + q1 * Wr3[128 + 64 + d];
    #pragma unroll
    for (int off = 32; off > 0; off >>= 1) {
        p0 += __shfl_down(p0, off);
        p1 += __shfl_down(p1, off);
    }
    if (d == 0) {
        float l0 = p0 + br3[0], l1 = p1 + br3[1];
        float mx = fmaxf(l0, l1);
        float e0v = expf(l0 - mx), e1v = expf(l1 - mx), s = e0v + e1v;
        out[n * 2 + 0] = e0v / s;
        out[n * 2 + 1] = e1v / s;
        out[2 * N_NODES + n * 2 + 0] = l0;
        out[2 * N_NODES + n * 2 + 1] = l1;
    }
}

extern "C" void kernel_launch(void* const* d_in, const int* in_sizes, int n_in,
                              void* d_out, int out_size, void* d_ws, size_t ws_size,
                              hipStream_t stream) {
    const float* J    = (const float*)d_in[0];
    const float* b    = (const float*)d_in[1];
    const int*   row  = (const int*)d_in[2];
    const int*   col  = (const int*)d_in[3];
    const float* Wm1  = (const float*)d_in[4];
    const float* bm1  = (const float*)d_in[5];
    const float* Wm2  = (const float*)d_in[6];
    const float* bm2  = (const float*)d_in[7];
    const float* Wm3  = (const float*)d_in[8];
    const float* bm3  = (const float*)d_in[9];
    const float* W_ih = (const float*)d_in[10];
    const float* W_hh = (const float*)d_in[11];
    const float* b_ih = (const float*)d_in[12];
    const float* b_hh = (const float*)d_in[13];
    const float* Wr1  = (const float*)d_in[14];
    const float* br1  = (const float*)d_in[15];
    const float* Wr2  = (const float*)d_in[16];
    const float* br2  = (const float*)d_in[17];
    const float* Wr3  = (const float*)d_in[18];
    const float* br3  = (const float*)d_in[19];
    float* out = (float*)d_out;

    // fp32 regions
    float* ws     = (float*)d_ws;
    float* nm2    = ws;  ws += N_NODES * 128;
    float* Wr1t   = ws;  ws += 64 * 128;
    float* Wr2t   = ws;  ws += 128 * 128;
    float* extraW = ws;  ws += 4 * 128;
    float* degf   = ws;  ws += N_NODES;
    float* jvv    = ws;  ws += N_EDGES;
    float* PQ     = ws;  ws += N_NODES * 256;
    // fp16-pair regions (u16 storage)
    u16* us    = (u16*)ws;
    u16* h_hi  = us;  us += N_NODES * 64;
    u16* h_lo  = us;  us += N_NODES * 64;
    u16* W2_h  = us;  us += 128 * 128;
    u16* W2_l  = us;  us += 128 * 128;
    u16* Wab_h = us;  us += 256 * 64;
    u16* Wab_l = us;  us += 256 * 64;
    u16* W3_h  = us;  us += 64 * 128;
    u16* W3_l  = us;  us += 64 * 128;
    u16* Wih_h = us;  us += 192 * 64;
    u16* Wih_l = us;  us += 192 * 64;
    u16* Whh_h = us;  us += 192 * 64;
    u16* Whh_l = us;  us += 192 * 64;

    hipMemsetAsync(degf, 0, N_NODES * sizeof(float), stream);
    prep_edges_k<<<(N_EDGES + 255) / 256, 256, 0, stream>>>(J, row, col, jvv, degf);
    convw_k<<<258, 256, 0, stream>>>(Wm1, bm1, Wm2, Wm3, W_ih, W_hh,
                                     W2_h, W2_l, Wab_h, Wab_l, W3_h, W3_l,
                                     Wih_h, Wih_l, Whh_h, Whh_l, extraW);
    transpose_k<<<(128 * 64 + 255) / 256, 256, 0, stream>>>(Wr1, Wr1t, 128, 64);
    transpose_k<<<(128 * 128 + 255) / 256, 256, 0, stream>>>(Wr2, Wr2t, 128, 128);

    hipMemsetAsync(h_hi, 0, N_NODES * 64 * sizeof(u16), stream);
    hipMemsetAsync(h_lo, 0, N_NODES * 64 * sizeof(u16), stream);
    hipMemsetAsync(nm2, 0, N_NODES * 128 * sizeof(float), stream);

    // initial PQ from h=0 (folded b-terms make PQ nonzero even at h=0)
    embed_k<<<N_NODES / 64, 256, 0, stream>>>(h_hi, h_lo, Wab_h, Wab_l, b, extraW, PQ);

    for (int s = 0; s < NSTEPS; s++) {
        msg7_k<<<N_EDGES / 64, 512, 0, stream>>>(PQ, row, col, jvv, extraW,
                                                 W2_h, W2_l, bm2, nm2);
        nodeGRU_k<<<N_NODES / 16, 256, 0, stream>>>(nm2, degf, W3_h, W3_l, bm3,
                                                    Wih_h, Wih_l, Whh_h, Whh_l,
                                                    b_ih, b_hh, Wab_h, Wab_l,
                                                    b, extraW, h_hi, h_lo, PQ);
    }
    readout_k<<<N_NODES / 4, 256, 0, stream>>>(h_hi, h_lo, Wr1t, br1, Wr2t, br2,
                                               Wr3, br3, out);
}

// Round 16
// 867.349 us; speedup vs baseline: 1.7254x; 1.7254x over previous
//
#include <hip/hip_runtime.h>
#include <math.h>

#define N_NODES 8000
#define N_EDGES 256000
#define NSTEPS 10
#define LO_SCALE 4096.0f
#define LO_INV   (1.0f/4096.0f)

typedef unsigned short u16;
typedef unsigned int   u32;
typedef _Float16 h8_t __attribute__((ext_vector_type(8)));
typedef float f32x4 __attribute__((ext_vector_type(4)));

#define MFMA(a, b, c) __builtin_amdgcn_mfma_f32_16x16x32_f16((a), (b), (c), 0, 0, 0)

// x ~= hi + lo/4096, relative error ~2^-22 (lo scaled to stay fp16-normal)
__device__ __forceinline__ void split2(float x, u16& hi, u16& lo) {
    _Float16 h = (_Float16)x;
    _Float16 l = (_Float16)((x - (float)h) * LO_SCALE);
    hi = __builtin_bit_cast(u16, h);
    lo = __builtin_bit_cast(u16, l);
}
__device__ __forceinline__ float h2f(u16 u) {
    return (float)__builtin_bit_cast(_Float16, u);
}
__device__ __forceinline__ float joinv(u16 hi, u16 lo) {
    return h2f(hi) + h2f(lo) * LO_INV;
}

union U8 { u16 s[8]; uint4 v; };

// ---------------- one-time prep kernels ----------------

__global__ __launch_bounds__(256)
void prep_edges_k(const float* __restrict__ J,
                  const int* __restrict__ row, const int* __restrict__ col,
                  float* __restrict__ jvv, float* __restrict__ degf) {
    int idx = blockIdx.x * 256 + threadIdx.x;
    if (idx < N_EDGES) {
        int r = row[idx], c = col[idx];
        jvv[idx] = J[(long)r * N_NODES + c];
        atomicAdd(&degf[r], 1.0f);
    }
}

// W2 pairs [128][128]; W1ab pairs [256][64]; W3 pairs [64][128];
// extraW f32 [4][128] = {Wm1[:,128], Wm1[:,129], Wm1[:,130], bm1};
// Wih pairs [192][64]; Whh pairs [192][64]  (torch-native row-major [out][in])
__global__ __launch_bounds__(256)
void convw_k(const float* __restrict__ Wm1, const float* __restrict__ bm1,
             const float* __restrict__ Wm2, const float* __restrict__ Wm3,
             const float* __restrict__ W_ih, const float* __restrict__ W_hh,
             u16* __restrict__ W2_h,  u16* __restrict__ W2_l,
             u16* __restrict__ Wab_h, u16* __restrict__ Wab_l,
             u16* __restrict__ W3_h,  u16* __restrict__ W3_l,
             u16* __restrict__ Wih_h, u16* __restrict__ Wih_l,
             u16* __restrict__ Whh_h, u16* __restrict__ Whh_l,
             float* __restrict__ extraW) {
    int i = blockIdx.x * 256 + threadIdx.x;
    u16 hi, lo;
    if (i < 16384) {                       // W2 [j][k]
        split2(Wm2[i], hi, lo);
        W2_h[i] = hi; W2_l[i] = lo;
    } else if (i < 32768) {                // W1ab [256][64]
        int t = i - 16384; int j = t >> 6, k = t & 63;
        float src = (j < 128) ? Wm1[j * 131 + k] : Wm1[(j - 128) * 131 + 64 + k];
        split2(src, hi, lo);
        Wab_h[t] = hi; Wab_l[t] = lo;
    } else if (i < 40960) {                // W3 [64][128]
        int t = i - 32768;
        split2(Wm3[t], hi, lo);
        W3_h[t] = hi; W3_l[t] = lo;
    } else if (i < 41472) {                // extraW
        int t = i - 40960; int rr = t >> 7, j = t & 127;
        extraW[t] = (rr < 3) ? Wm1[j * 131 + 128 + rr] : bm1[j];
    } else if (i < 53760) {                // Wih [192][64]
        int t = i - 41472;
        split2(W_ih[t], hi, lo);
        Wih_h[t] = hi; Wih_l[t] = lo;
    } else if (i < 66048) {                // Whh [192][64]
        int t = i - 53760;
        split2(W_hh[t], hi, lo);
        Whh_h[t] = hi; Whh_l[t] = lo;
    }
}

// out[k*O + j] = in[j*K + k]
__global__ __launch_bounds__(256)
void transpose_k(const float* __restrict__ in, float* __restrict__ out, int O, int K) {
    int idx = blockIdx.x * 256 + threadIdx.x;
    if (idx < O * K) {
        int j = idx / K, k = idx - j * K;
        out[k * O + j] = in[idx];
    }
}

// ---------------- register-B pair-GEMM core (verified frag layout) ----------------

template <int NT, int K0>
__device__ __forceinline__ void load_bfrags(const u16* __restrict__ Wh,
                                            const u16* __restrict__ Wl,
                                            int wn, int l15, int g,
                                            h8_t (&bh)[NT][K0], h8_t (&bl)[NT][K0]) {
    #pragma unroll
    for (int jt = 0; jt < NT; jt++)
        #pragma unroll
        for (int k0 = 0; k0 < K0; k0++) {
            int off = (wn + jt * 16 + l15) * (K0 * 32) + k0 * 32 + g * 8;
            bh[jt][k0] = *(const h8_t*)(Wh + off);
            bl[jt][k0] = *(const h8_t*)(Wl + off);
        }
}

// A from swizzled LDS (chunk c of row r at (r*CH + (c^(r&7)))*8), B in registers.
template <int NT, int K0, int CH>
__device__ __forceinline__ void gemm_regB(const u16* Ah, const u16* Al,
                                          const h8_t (&bh)[NT][K0],
                                          const h8_t (&bl)[NT][K0],
                                          int et, int l15, int g,
                                          f32x4 (&accH)[NT], f32x4 (&accC)[NT]) {
    #pragma unroll
    for (int k0 = 0; k0 < K0; k0++) {
        int r = et * 16 + l15;
        int off = (r * CH + ((k0 * 4 + g) ^ (r & 7))) * 8;
        h8_t a_h = *(const h8_t*)(Ah + off);
        h8_t a_l = *(const h8_t*)(Al + off);
        #pragma unroll
        for (int jt = 0; jt < NT; jt++) {
            accH[jt] = MFMA(a_h, bh[jt][k0], accH[jt]);
            accC[jt] = MFMA(a_h, bl[jt][k0], accC[jt]);
            accC[jt] = MFMA(a_l, bh[jt][k0], accC[jt]);
        }
    }
}

// ---------------- edge kernel v8: msg6 structure + padded t2 + batched scatter ----------------
// 64 edges/block, 512 threads, 8 waves; wave w owns j-tile [w*16, w*16+16).
// LDS: one raw 33 KB buffer. Phase A: t1 pairs (2 x 16 KB). Phase B: t2 f32 [64][129].
__global__ __launch_bounds__(512, 6)
void msg8_k(const float* __restrict__ PQ,
            const int* __restrict__ row, const int* __restrict__ col,
            const float* __restrict__ jvv, const float* __restrict__ extraW,
            const u16* __restrict__ W2_h, const u16* __restrict__ W2_l,
            const float* __restrict__ bm2,
            float* __restrict__ nm2) {
    __shared__ float t2s[64 * 129];        // 33 KB; aliased for t1 pairs below
    __shared__ int rws[64];
    u16* AB0 = (u16*)t2s;                  // t1 hi pairs, 16 KB
    u16* AB1 = (u16*)t2s + 64 * 128;       // t1 lo pairs, next 16 KB
    const u16* Ah = AB0;
    const u16* Al = AB1;
    const int tid  = threadIdx.x;
    // XCD-aware bijective swizzle: 4000 blocks = 8 XCDs x 500 contiguous
    const int bid  = blockIdx.x;
    const int e0   = ((bid & 7) * 500 + (bid >> 3)) * 64;
    const int lane = tid & 63;
    const int w    = tid >> 6;
    const int l15  = lane & 15;
    const int g    = lane >> 4;

    // W2 fragments for this wave's 16-wide j-tile (8 x h8_t = 32 VGPR)
    h8_t bh[1][4], bl[1][4];
    load_bfrags<1, 4>(W2_h, W2_l, w * 16, l15, g, bh, bl);

    // ---- t1 assembly: thread -> edge e=tid>>3, j-eighth jq=tid&7 ----
    {
        int e = tid >> 3, jq = tid & 7;
        int nr = row[e0 + e], nc = col[e0 + e];
        float jv = jvv[e0 + e];
        if (jq == 0) rws[e] = nr;
        const float* Pp = PQ + nr * 256;          // P' = h@W1a^T + b*w129 + bm1
        const float* Qp = PQ + nc * 256 + 128;    // Q' = h@W1b^T + b*w130
        #pragma unroll
        for (int cc = 0; cc < 2; cc++) {
            int jb = jq * 16 + cc * 8;
            float4 p0 = *(const float4*)(Pp + jb);
            float4 p1 = *(const float4*)(Pp + jb + 4);
            float4 q0 = *(const float4*)(Qp + jb);
            float4 q1 = *(const float4*)(Qp + jb + 4);
            float4 wA = *(const float4*)(extraW + jb);
            float4 wB = *(const float4*)(extraW + jb + 4);
            float pv[8] = {p0.x, p0.y, p0.z, p0.w, p1.x, p1.y, p1.z, p1.w};
            float qv[8] = {q0.x, q0.y, q0.z, q0.w, q1.x, q1.y, q1.z, q1.w};
            float wv[8] = {wA.x, wA.y, wA.z, wA.w, wB.x, wB.y, wB.z, wB.w};
            U8 uh, ul;
            #pragma unroll
            for (int m = 0; m < 8; m++) {
                float v = fmaxf(pv[m] + qv[m] + jv * wv[m], 0.f);
                u16 hi, lo; split2(v, hi, lo);
                uh.s[m] = hi; ul.s[m] = lo;
            }
            int c = jq * 2 + cc;
            int dst = (e * 16 + (c ^ (e & 7))) * 8;
            *(uint4*)(AB0 + dst) = uh.v;
            *(uint4*)(AB1 + dst) = ul.v;
        }
    }
    __syncthreads();

    // ---- layer 2 GEMM: 4 et-tiles x 1 j-tile, t2 in registers ----
    f32x4 t2r[4];
    {
        const float bv0 = bm2[w * 16 + l15];
        #pragma unroll
        for (int et = 0; et < 4; et++) {
            f32x4 accH[1], accC[1];
            accH[0] = f32x4{bv0, bv0, bv0, bv0};
            accC[0] = f32x4{0.f, 0.f, 0.f, 0.f};
            gemm_regB<1, 4, 16>(Ah, Al, bh, bl, et, l15, g, accH, accC);
            #pragma unroll
            for (int r = 0; r < 4; r++)
                t2r[et][r] = fmaxf(accH[0][r] + accC[0][r] * LO_INV, 0.f);
        }
    }
    __syncthreads();                       // everyone done reading t1 pairs

    // ---- spill t2 (f32, padded [64][129] -> conflict-free writes) ----
    #pragma unroll
    for (int et = 0; et < 4; et++) {
        int j = w * 16 + l15;
        #pragma unroll
        for (int r = 0; r < 4; r++)
            t2s[(et * 16 + g * 4 + r) * 129 + j] = t2r[et][r];
    }
    __syncthreads();

    // ---- scatter: rows sorted -> batched preload, run-accumulate, few atomics ----
    {
        int d2 = tid & 127, q = tid >> 7;
        int ebeg = q * 16;
        float vals[16]; int rr[16];
        #pragma unroll
        for (int i = 0; i < 16; i++) {
            vals[i] = t2s[(ebeg + i) * 129 + d2];
            rr[i]   = rws[ebeg + i];
        }
        float a = vals[0];
        int cur = rr[0];
        #pragma unroll
        for (int i = 1; i < 16; i++) {
            if (rr[i] != cur) {
                atomicAdd(&nm2[cur * 128 + d2], a);
                a = vals[i]; cur = rr[i];
            } else {
                a += vals[i];
            }
        }
        atomicAdd(&nm2[cur * 128 + d2], a);
    }
}

// ---------------- fused node kernel: nodeL3 + GRU + embed (16 nodes/block) ----------------
__global__ __launch_bounds__(256)
void nodeGRU_k(float* __restrict__ nm2, const float* __restrict__ degf,
               const u16* __restrict__ W3_h, const u16* __restrict__ W3_l,
               const float* __restrict__ bm3,
               const u16* __restrict__ Wih_h, const u16* __restrict__ Wih_l,
               const u16* __restrict__ Whh_h, const u16* __restrict__ Whh_l,
               const float* __restrict__ b_ih, const float* __restrict__ b_hh,
               const u16* __restrict__ Wab_h, const u16* __restrict__ Wab_l,
               const float* __restrict__ bvec, const float* __restrict__ extraW,
               u16* __restrict__ h_hi, u16* __restrict__ h_lo,
               float* __restrict__ PQ) {
    __shared__ u16 nm2A[2][16 * 128];   // 8 KB  (nm2 pairs, CH=16)
    __shared__ u16 hA[2][16 * 64];      // 4 KB  (h pairs,   CH=8)
    __shared__ u16 nmA[2][16 * 64];     // 4 KB  (nm pairs,  CH=8)
    __shared__ u16 hnA[2][16 * 64];     // 4 KB  (h_new pairs, CH=8)
    const int tid = threadIdx.x;
    const int n0  = blockIdx.x * 16;
    const int lane = tid & 63, w = tid >> 6, l15 = lane & 15, g = lane >> 4;

    // ---- phase 0: stage nm2 pairs (and zero nm2), stage h pairs ----
    {
        int n = tid >> 4, kq = tid & 15;       // 16 nodes x 16 chunks
        float* src = nm2 + (n0 + n) * 128 + kq * 8;
        U8 uh, ul;
        #pragma unroll
        for (int m = 0; m < 8; m++) {
            u16 hi, lo; split2(src[m], hi, lo);
            uh.s[m] = hi; ul.s[m] = lo;
        }
        int dst = (n * 16 + (kq ^ (n & 7))) * 8;
        *(uint4*)(nm2A[0] + dst) = uh.v;
        *(uint4*)(nm2A[1] + dst) = ul.v;
        #pragma unroll
        for (int m = 0; m < 2; m++)
            ((f32x4*)src)[m] = f32x4{0.f, 0.f, 0.f, 0.f};   // clear for next step
        if (tid < 128) {
            int nh = tid >> 3, c = tid & 7;
            int dsth = (nh * 8 + (c ^ (nh & 7))) * 8;
            *(uint4*)(hA[0] + dsth) = *(const uint4*)(h_hi + (n0 + nh) * 64 + c * 8);
            *(uint4*)(hA[1] + dsth) = *(const uint4*)(h_lo + (n0 + nh) * 64 + c * 8);
        }
    }
    __syncthreads();

    // ---- phase 1: nm = nm2 @ W3^T + deg*bm3  -> nmA pairs ----
    {
        h8_t bh[1][4], bl[1][4];
        load_bfrags<1, 4>(W3_h, W3_l, w * 16, l15, g, bh, bl);
        const int j = w * 16 + l15;
        const float bj = bm3[j];
        f32x4 accH[1], accC[1];
        accH[0] = f32x4{0.f, 0.f, 0.f, 0.f};
        accC[0] = f32x4{0.f, 0.f, 0.f, 0.f};
        gemm_regB<1, 4, 16>(nm2A[0], nm2A[1], bh, bl, 0, l15, g, accH, accC);
        #pragma unroll
        for (int r = 0; r < 4; r++) {
            int n = g * 4 + r;
            float v = accH[0][r] + accC[0][r] * LO_INV + degf[n0 + n] * bj;
            u16 hi, lo; split2(v, hi, lo);
            int addr = (n * 8 + ((j >> 3) ^ (n & 7))) * 8 + (j & 7);
            nmA[0][addr] = hi; nmA[1][addr] = lo;
        }
    }
    __syncthreads();

    // ---- phase 2: GRU via MFMA; wave w owns d-tile [w*16, w*16+16) ----
    {
        h8_t bihH[3][2], bihL[3][2], bhhH[3][2], bhhL[3][2];
        #pragma unroll
        for (int gate = 0; gate < 3; gate++)
            #pragma unroll
            for (int k0 = 0; k0 < 2; k0++) {
                int off = (gate * 64 + w * 16 + l15) * 64 + k0 * 32 + g * 8;
                bihH[gate][k0] = *(const h8_t*)(Wih_h + off);
                bihL[gate][k0] = *(const h8_t*)(Wih_l + off);
                bhhH[gate][k0] = *(const h8_t*)(Whh_h + off);
                bhhL[gate][k0] = *(const h8_t*)(Whh_l + off);
            }
        const int d = w * 16 + l15;
        const float bi0 = b_ih[d], bi1 = b_ih[64 + d], bi2 = b_ih[128 + d];
        const float bh0 = b_hh[d], bh1 = b_hh[64 + d], bh2 = b_hh[128 + d];

        f32x4 giH[3], giC[3], ghH[3], ghC[3];
        giH[0] = f32x4{bi0, bi0, bi0, bi0};
        giH[1] = f32x4{bi1, bi1, bi1, bi1};
        giH[2] = f32x4{bi2, bi2, bi2, bi2};
        ghH[0] = f32x4{bh0, bh0, bh0, bh0};
        ghH[1] = f32x4{bh1, bh1, bh1, bh1};
        ghH[2] = f32x4{bh2, bh2, bh2, bh2};
        #pragma unroll
        for (int gate = 0; gate < 3; gate++) {
            giC[gate] = f32x4{0.f, 0.f, 0.f, 0.f};
            ghC[gate] = f32x4{0.f, 0.f, 0.f, 0.f};
        }
        #pragma unroll
        for (int k0 = 0; k0 < 2; k0++) {
            int off = (l15 * 8 + ((k0 * 4 + g) ^ (l15 & 7))) * 8;
            h8_t anH = *(const h8_t*)(nmA[0] + off);
            h8_t anL = *(const h8_t*)(nmA[1] + off);
            h8_t ahH = *(const h8_t*)(hA[0] + off);
            h8_t ahL = *(const h8_t*)(hA[1] + off);
            #pragma unroll
            for (int gate = 0; gate < 3; gate++) {
                giH[gate] = MFMA(anH, bihH[gate][k0], giH[gate]);
                giC[gate] = MFMA(anH, bihL[gate][k0], giC[gate]);
                giC[gate] = MFMA(anL, bihH[gate][k0], giC[gate]);
                ghH[gate] = MFMA(ahH, bhhH[gate][k0], ghH[gate]);
                ghC[gate] = MFMA(ahH, bhhL[gate][k0], ghC[gate]);
                ghC[gate] = MFMA(ahL, bhhH[gate][k0], ghC[gate]);
            }
        }
        #pragma unroll
        for (int r = 0; r < 4; r++) {
            int n = g * 4 + r;
            float i_r = giH[0][r] + giC[0][r] * LO_INV;
            float i_z = giH[1][r] + giC[1][r] * LO_INV;
            float i_n = giH[2][r] + giC[2][r] * LO_INV;
            float h_r = ghH[0][r] + ghC[0][r] * LO_INV;
            float h_z = ghH[1][r] + ghC[1][r] * LO_INV;
            float h_n = ghH[2][r] + ghC[2][r] * LO_INV;
            int addr = (n * 8 + ((d >> 3) ^ (n & 7))) * 8 + (d & 7);
            float hv = joinv(hA[0][addr], hA[1][addr]);
            float rg = 1.f / (1.f + expf(-(i_r + h_r)));
            float zg = 1.f / (1.f + expf(-(i_z + h_z)));
            float ng = tanhf(i_n + rg * h_n);
            float v  = (1.f - zg) * ng + zg * hv;
            u16 hi, lo; split2(v, hi, lo);
            h_hi[(n0 + n) * 64 + d] = hi;
            h_lo[(n0 + n) * 64 + d] = lo;
            hnA[0][addr] = hi; hnA[1][addr] = lo;
        }
    }
    __syncthreads();

    // ---- phase 3: PQ = h_new @ [W1a|W1b]^T + folded b-terms (f32 out) ----
    {
        h8_t bh[4][2], bl[4][2];
        load_bfrags<4, 2>(Wab_h, Wab_l, w * 64, l15, g, bh, bl);
        f32x4 accH[4], accC[4];
        #pragma unroll
        for (int jt = 0; jt < 4; jt++) {
            accH[jt] = f32x4{0.f, 0.f, 0.f, 0.f};
            accC[jt] = f32x4{0.f, 0.f, 0.f, 0.f};
        }
        gemm_regB<4, 2, 8>(hnA[0], hnA[1], bh, bl, 0, l15, g, accH, accC);
        #pragma unroll
        for (int jt = 0; jt < 4; jt++) {
            int j = w * 64 + jt * 16 + l15;
            #pragma unroll
            for (int r = 0; r < 4; r++) {
                int n = g * 4 + r;
                float bn = bvec[n0 + n];
                float v = accH[jt][r] + accC[jt][r] * LO_INV;
                if (j < 128) v += bn * extraW[128 + j] + extraW[384 + j];
                else         v += bn * extraW[256 + (j - 128)];
                PQ[(n0 + n) * 256 + j] = v;
            }
        }
    }
}

// ---------------- node kernel: initial PQ (h=0), f32 out ----------------
__global__ __launch_bounds__(256)
void embed_k(const u16* __restrict__ h_hi, const u16* __restrict__ h_lo,
             const u16* __restrict__ Wab_h, const u16* __restrict__ Wab_l,
             const float* __restrict__ bvec, const float* __restrict__ extraW,
             float* __restrict__ PQ) {
    __shared__ u16 AB[2][64 * 64];
    const u16* Ah = AB[0];
    const u16* Al = AB[1];
    const int tid = threadIdx.x;
    const int n0  = blockIdx.x * 64;
    const int lane = tid & 63, w = tid >> 6, l15 = lane & 15, g = lane >> 4;

    h8_t bh[4][2], bl[4][2];
    load_bfrags<4, 2>(Wab_h, Wab_l, w * 64, l15, g, bh, bl);

    {
        int n = tid >> 2, seg = tid & 3;
        #pragma unroll
        for (int cc = 0; cc < 2; cc++) {
            int c = seg * 2 + cc;
            int dst = (n * 8 + (c ^ (n & 7))) * 8;
            *(uint4*)(AB[0] + dst) = *(const uint4*)(h_hi + (n0 + n) * 64 + c * 8);
            *(uint4*)(AB[1] + dst) = *(const uint4*)(h_lo + (n0 + n) * 64 + c * 8);
        }
    }
    __syncthreads();

    #pragma unroll
    for (int et = 0; et < 4; et++) {
        f32x4 accH[4], accC[4];
        #pragma unroll
        for (int jt = 0; jt < 4; jt++) {
            accH[jt] = f32x4{0.f, 0.f, 0.f, 0.f};
            accC[jt] = f32x4{0.f, 0.f, 0.f, 0.f};
        }
        gemm_regB<4, 2, 8>(Ah, Al, bh, bl, et, l15, g, accH, accC);
        #pragma unroll
        for (int jt = 0; jt < 4; jt++) {
            int j = w * 64 + jt * 16 + l15;
            #pragma unroll
            for (int r = 0; r < 4; r++) {
                int n = et * 16 + g * 4 + r;
                float bn = bvec[n0 + n];
                float v = accH[jt][r] + accC[jt][r] * LO_INV;
                if (j < 128) v += bn * extraW[128 + j] + extraW[384 + j];
                else         v += bn * extraW[256 + (j - 128)];
                PQ[(n0 + n) * 256 + j] = v;
            }
        }
    }
}

// ---------------- readout MLP + softmax ----------------
__global__ __launch_bounds__(256)
void readout_k(const u16* __restrict__ h_hi, const u16* __restrict__ h_lo,
               const float* __restrict__ Wr1t, const float* __restrict__ br1,
               const float* __restrict__ Wr2t, const float* __restrict__ br2,
               const float* __restrict__ Wr3,  const float* __restrict__ br3,
               float* __restrict__ out) {
    __shared__ float hs[4][64], r1s[4][128];
    int tid = threadIdx.x, g = tid >> 6, d = tid & 63;
    int n = blockIdx.x * 4 + g;
    hs[g][d] = joinv(h_hi[n * 64 + d], h_lo[n * 64 + d]);
    __syncthreads();
    float a0 = br1[d], a1 = br1[64 + d];
    for (int k = 0; k < 64; k++) {
        float v = hs[g][k];
        a0 = fmaf(v, Wr1t[k * 128 + d],      a0);
        a1 = fmaf(v, Wr1t[k * 128 + 64 + d], a1);
    }
    r1s[g][d] = fmaxf(a0, 0.f); r1s[g][64 + d] = fmaxf(a1, 0.f);
    __syncthreads();
    a0 = br2[d]; a1 = br2[64 + d];
    for (int k = 0; k < 128; k++) {
        float v = r1s[g][k];
        a0 = fmaf(v, Wr2t[k * 128 + d],      a0);
        a1 = fmaf(v, Wr2t[k * 128 + 64 + d], a1);
    }
    float q0 = fmaxf(a0, 0.f), q1 = fmaxf(a1, 0.f);
    float p0 = q0 * Wr3[d]       + q1 * Wr3[64 + d];
    float p1 = q0 * Wr3[128 + d] + q1 * Wr3[128 + 64 + d];
    #pragma unroll
    for (int off = 32; off > 0; off >>= 1) {
        p0 += __shfl_down(p0, off);
        p1 += __shfl_down(p1, off);
    }
    if (d == 0) {
        float l0 = p0 + br3[0], l1 = p1 + br3[1];
        float mx = fmaxf(l0, l1);
        float e0v = expf(l0 - mx), e1v = expf(l1 - mx), s = e0v + e1v;
        out[n * 2 + 0] = e0v / s;
        out[n * 2 + 1] = e1v / s;
        out[2 * N_NODES + n * 2 + 0] = l0;
        out[2 * N_NODES + n * 2 + 1] = l1;
    }
}

extern "C" void kernel_launch(void* const* d_in, const int* in_sizes, int n_in,
                              void* d_out, int out_size, void* d_ws, size_t ws_size,
                              hipStream_t stream) {
    const float* J    = (const float*)d_in[0];
    const float* b    = (const float*)d_in[1];
    const int*   row  = (const int*)d_in[2];
    const int*   col  = (const int*)d_in[3];
    const float* Wm1  = (const float*)d_in[4];
    const float* bm1  = (const float*)d_in[5];
    const float* Wm2  = (const float*)d_in[6];
    const float* bm2  = (const float*)d_in[7];
    const float* Wm3  = (const float*)d_in[8];
    const float* bm3  = (const float*)d_in[9];
    const float* W_ih = (const float*)d_in[10];
    const float* W_hh = (const float*)d_in[11];
    const float* b_ih = (const float*)d_in[12];
    const float* b_hh = (const float*)d_in[13];
    const float* Wr1  = (const float*)d_in[14];
    const float* br1  = (const float*)d_in[15];
    const float* Wr2  = (const float*)d_in[16];
    const float* br2  = (const float*)d_in[17];
    const float* Wr3  = (const float*)d_in[18];
    const float* br3  = (const float*)d_in[19];
    float* out = (float*)d_out;

    // fp32 regions
    float* ws     = (float*)d_ws;
    float* nm2    = ws;  ws += N_NODES * 128;
    float* Wr1t   = ws;  ws += 64 * 128;
    float* Wr2t   = ws;  ws += 128 * 128;
    float* extraW = ws;  ws += 4 * 128;
    float* degf   = ws;  ws += N_NODES;
    float* jvv    = ws;  ws += N_EDGES;
    float* PQ     = ws;  ws += N_NODES * 256;
    // fp16-pair regions (u16 storage)
    u16* us    = (u16*)ws;
    u16* h_hi  = us;  us += N_NODES * 64;
    u16* h_lo  = us;  us += N_NODES * 64;
    u16* W2_h  = us;  us += 128 * 128;
    u16* W2_l  = us;  us += 128 * 128;
    u16* Wab_h = us;  us += 256 * 64;
    u16* Wab_l = us;  us += 256 * 64;
    u16* W3_h  = us;  us += 64 * 128;
    u16* W3_l  = us;  us += 64 * 128;
    u16* Wih_h = us;  us += 192 * 64;
    u16* Wih_l = us;  us += 192 * 64;
    u16* Whh_h = us;  us += 192 * 64;
    u16* Whh_l = us;  us += 192 * 64;

    hipMemsetAsync(degf, 0, N_NODES * sizeof(float), stream);
    prep_edges_k<<<(N_EDGES + 255) / 256, 256, 0, stream>>>(J, row, col, jvv, degf);
    convw_k<<<258, 256, 0, stream>>>(Wm1, bm1, Wm2, Wm3, W_ih, W_hh,
                                     W2_h, W2_l, Wab_h, Wab_l, W3_h, W3_l,
                                     Wih_h, Wih_l, Whh_h, Whh_l, extraW);
    transpose_k<<<(128 * 64 + 255) / 256, 256, 0, stream>>>(Wr1, Wr1t, 128, 64);
    transpose_k<<<(128 * 128 + 255) / 256, 256, 0, stream>>>(Wr2, Wr2t, 128, 128);

    hipMemsetAsync(h_hi, 0, N_NODES * 64 * sizeof(u16), stream);
    hipMemsetAsync(h_lo, 0, N_NODES * 64 * sizeof(u16), stream);
    hipMemsetAsync(nm2, 0, N_NODES * 128 * sizeof(float), stream);

    // initial PQ from h=0 (folded b-terms make PQ nonzero even at h=0)
    embed_k<<<N_NODES / 64, 256, 0, stream>>>(h_hi, h_lo, Wab_h, Wab_l, b, extraW, PQ);

    for (int s = 0; s < NSTEPS; s++) {
        msg8_k<<<N_EDGES / 64, 512, 0, stream>>>(PQ, row, col, jvv, extraW,
                                                 W2_h, W2_l, bm2, nm2);
        nodeGRU_k<<<N_NODES / 16, 256, 0, stream>>>(nm2, degf, W3_h, W3_l, bm3,
                                                    Wih_h, Wih_l, Whh_h, Whh_l,
                                                    b_ih, b_hh, Wab_h, Wab_l,
                                                    b, extraW, h_hi, h_lo, PQ);
    }
    readout_k<<<N_NODES / 4, 256, 0, stream>>>(h_hi, h_lo, Wr1t, br1, Wr2t, br2,
                                               Wr3, br3, out);
}